// Round 6
// baseline (40.262 us; speedup 1.0000x reference)
//
#include <hip/hip_runtime.h>
#include <math.h>

#define A_N 200000
#define B_N 8
#define M_N 32
#define THREADS 256
#define APT 2                        // anchors per thread
#define APB (THREADS * APT)          // anchors per block = 512
#define BPI ((A_N + APB - 1) / APB)  // blocks per image = 391
#define NPART (B_N * BPI)

__device__ __forceinline__ float sl1(float d) {
    d = fabsf(d);
    return (d <= (1.0f / 9.0f)) ? (4.5f * d * d) : (d - (1.0f / 18.0f));
}

// (256,4): allow up to 128 VGPR (no 8-wave heuristic squeeze), still >=4 waves/EU.
// R3 lesson: (128,8) forced VGPR=32 -> 38MB scratch spill. R1 lesson: default
// heuristic picked VGPR=48 -> mov inflation. 128-cap is the middle ground.
__global__ __launch_bounds__(THREADS, 4)
void focal_main(const float* __restrict__ cls,
                const float4* __restrict__ reg,
                const float4* __restrict__ anchors,
                const float* __restrict__ ann,
                float* __restrict__ pc, float* __restrict__ pr, float* __restrict__ pn)
{
    const int blk = blockIdx.x;
    const int b   = blockIdx.y;
    const int tid = threadIdx.x;

    __shared__ float wred[THREADS / 64][3];

    // Boxes are wave-uniform: read straight from global with uniform addresses
    // (scalar-load path; SMEM pipe idle otherwise). No LDS staging, no barrier.
    const float* __restrict__ annb = ann + (size_t)b * M_N * 5;

    const int abase = blk * APB + tid;

    float ax1[APT], ay1[APT], ax2[APT], ay2[APT], areaA[APT], pclsv[APT];
    unsigned int best[APT];   // (bits(t) & ~31) | (31-j) ; t = inter/S monotone in IoU
    #pragma unroll
    for (int k = 0; k < APT; k++) {
        int a  = abase + k * THREADS;
        int al = (a < A_N) ? a : (A_N - 1);
        float4 v = anchors[al];
        ax1[k] = v.x; ay1[k] = v.y; ax2[k] = v.z; ay2[k] = v.w;
        areaA[k] = (v.z - v.x) * (v.w - v.y);
        best[k] = 0u;
        pclsv[k] = cls[((size_t)b * A_N + al) * 4];   // channel 0 only contributes
    }

    #pragma unroll 8
    for (int j = 0; j < M_N; j++) {
        float bx1 = annb[j * 5 + 0];
        float by1 = annb[j * 5 + 1];
        float bx2 = annb[j * 5 + 2];
        float by2 = annb[j * 5 + 3];
        float ab  = (bx2 - bx1) * (by2 - by1);
        #pragma unroll
        for (int k = 0; k < APT; k++) {
            float iw = fminf(ax2[k], bx2) - fmaxf(ax1[k], bx1);
            float ih = fminf(ay2[k], by2) - fmaxf(ay1[k], by1);
            iw = fmaxf(iw, 0.0f);
            ih = fmaxf(ih, 0.0f);
            float inter = iw * ih;
            float S = areaA[k] + ab;                    // S >= 128 always (ua = S - inter > 0)
            float t = inter * __builtin_amdgcn_rcpf(S); // trans pipe; iou = t/(1-t) monotone
            // pack argmax into the low 5 bits: equal (masked) t -> smaller j wins = first-argmax
            unsigned int key = (__float_as_uint(t) & 0xFFFFFFE0u) | (unsigned int)(31 - j);
            best[k] = max(best[k], key);
        }
    }

    float cls_sum = 0.0f, reg_sum = 0.0f, npos = 0.0f;
    #pragma unroll
    for (int k = 0; k < APT; k++) {
        int a = abase + k * THREADS;
        if (a >= A_N) continue;
        float bt = __uint_as_float(best[k] & 0xFFFFFFE0u);
        int   bj = 31 - (int)(best[k] & 31u);
        // iou >= 0.5 <=> t >= 1/3 ; iou < 0.4 <=> t < 2/7
        bool pos = bt >= (1.0f / 3.0f);
        bool neg = bt < (2.0f / 7.0f);
        float p = __builtin_amdgcn_fmed3f(pclsv[k], 1e-5f, 1.0f - 1e-5f);
        float q    = pos ? p : (1.0f - p);
        float coef = pos ? 0.25f : 0.75f;
        float omq  = 1.0f - q;
        float term = coef * omq * omq * (-__logf(q));
        cls_sum += (pos || neg) ? term : 0.0f;
        npos    += pos ? 1.0f : 0.0f;
        if (pos) {   // rare: exec-z skipped for most waves; divergent loads are L2-hot
            const float* bp = annb + bj * 5;
            float gx1 = bp[0], gy1 = bp[1], gx2 = bp[2], gy2 = bp[3];
            float aw = ax2[k] - ax1[k], ah = ay2[k] - ay1[k];
            float acx = ax1[k] + 0.5f * aw, acy = ay1[k] + 0.5f * ah;
            float gwr = gx2 - gx1, ghr = gy2 - gy1;
            float gcx = gx1 + 0.5f * gwr, gcy = gy1 + 0.5f * ghr;
            float gw = fmaxf(gwr, 1.0f), gh = fmaxf(ghr, 1.0f);
            float4 r = reg[(size_t)b * A_N + a];
            float rt0 = ((gcx - acx) / aw) / 0.1f;
            float rt1 = ((gcy - acy) / ah) / 0.1f;
            float rt2 = __logf(gw / aw) / 0.2f;
            float rt3 = __logf(gh / ah) / 0.2f;
            reg_sum += sl1(rt0 - r.x) + sl1(rt1 - r.y) + sl1(rt2 - r.z) + sl1(rt3 - r.w);
        }
    }

    // wave reduce (64 lanes)
    #pragma unroll
    for (int off = 32; off > 0; off >>= 1) {
        cls_sum += __shfl_down(cls_sum, off);
        reg_sum += __shfl_down(reg_sum, off);
        npos    += __shfl_down(npos, off);
    }
    int wid = tid >> 6;
    if ((tid & 63) == 0) {
        wred[wid][0] = cls_sum; wred[wid][1] = reg_sum; wred[wid][2] = npos;
    }
    __syncthreads();
    if (tid == 0) {
        float c = 0.0f, r = 0.0f, n = 0.0f;
        #pragma unroll
        for (int w = 0; w < THREADS / 64; w++) {
            c += wred[w][0]; r += wred[w][1]; n += wred[w][2];
        }
        int idx = b * BPI + blk;
        pc[idx] = c; pr[idx] = r; pn[idx] = n;   // SoA, every slot written each launch
    }
}

__global__ __launch_bounds__(512)
void focal_reduce(const float* __restrict__ pc, const float* __restrict__ pr,
                  const float* __restrict__ pn, float* __restrict__ out)
{
    __shared__ float scl[B_N], srg[B_N];
    int tid  = threadIdx.x;        // 512 threads = 8 waves, wave w handles image w
    int w    = tid >> 6;
    int lane = tid & 63;
    float cs = 0.0f, rs = 0.0f, np = 0.0f;
    for (int i = lane; i < BPI; i += 64) {     // coalesced SoA reads
        cs += pc[w * BPI + i];
        rs += pr[w * BPI + i];
        np += pn[w * BPI + i];
    }
    #pragma unroll
    for (int off = 32; off > 0; off >>= 1) {
        cs += __shfl_down(cs, off);
        rs += __shfl_down(rs, off);
        np += __shfl_down(np, off);
    }
    if (lane == 0) {
        scl[w] = cs / fmaxf(np, 1.0f);
        srg[w] = (np > 0.0f) ? rs / (4.0f * np) : 0.0f;
    }
    __syncthreads();
    if (tid == 0) {
        float c = 0.0f, r = 0.0f;
        #pragma unroll
        for (int i = 0; i < B_N; i++) { c += scl[i]; r += srg[i]; }
        out[0] = c / (float)B_N;
        out[1] = r / (float)B_N;
    }
}

extern "C" void kernel_launch(void* const* d_in, const int* in_sizes, int n_in,
                              void* d_out, int out_size, void* d_ws, size_t ws_size,
                              hipStream_t stream)
{
    const float*  cls     = (const float*)d_in[0];
    const float4* reg     = (const float4*)d_in[1];
    const float4* anchors = (const float4*)d_in[2];
    const float*  ann     = (const float*)d_in[3];
    float* pc = (float*)d_ws;              // [NPART]
    float* pr = pc + NPART;                // [NPART]
    float* pn = pr + NPART;                // [NPART]
    float* out = (float*)d_out;

    dim3 grid(BPI, B_N);
    focal_main<<<grid, THREADS, 0, stream>>>(cls, reg, anchors, ann, pc, pr, pn);
    focal_reduce<<<1, 512, 0, stream>>>(pc, pr, pn, out);
}